// Round 5
// baseline (1001.940 us; speedup 1.0000x reference)
//
#include <hip/hip_runtime.h>
#include <hip/hip_cooperative_groups.h>
#include <math.h>

namespace cg = cooperative_groups;

#define NN 4096
#define DD 512
#define FF 512
#define CAP 256
#define SCALE 0.08838834764831845f

typedef unsigned short u16;
typedef __attribute__((ext_vector_type(8))) short short8;
typedef __attribute__((ext_vector_type(8))) unsigned short ushort8;
typedef __attribute__((ext_vector_type(4))) float floatx4;

__device__ __forceinline__ float bf2f(u16 u) {
    union { unsigned int i; float f; } x; x.i = ((unsigned int)u) << 16; return x.f;
}
__device__ __forceinline__ u16 f2bf(float f) {
    union { float f; unsigned int i; } x; x.f = f;
    unsigned int r = (x.i + 0x7FFFu + ((x.i >> 16) & 1u)) >> 16;
    return (u16)r;
}
__device__ __forceinline__ void gld_lds16(const void* g, void* l) {
    __builtin_amdgcn_global_load_lds((const __attribute__((address_space(1))) void*)g,
                                     (__attribute__((address_space(3))) void*)l, 16, 0, 0);
}

struct KArgs {
    const float* nfeat; const int* mask;
    const float* ln1_g; const float* ln1_b; const float* ln2_g; const float* ln2_b;
    const float* w[6]; const float* bias[6];
    float* x; u16* xb; u16* qkv; u16* o; u16* m1;
    u16* wc; float* c0; float* c1; float* S0; float* P;
    int* idx; int* cnt; float* out;
};

// ================================================================ stage bodies

// setup: fold weights (3 groups/block), build idx (8 rows/block), init stats (8 rows/block)
__device__ void setup_body(const KArgs& a, int bid, int t, int* cbar) {
    const int wave = t >> 6, lane = t & 63;
    // --- fold: group gid = bid*3+it; r = gid>>7 (region), nb = gid&127; 4 rows n
    for (int it = 0; it < 3; it++) {
        int gid = bid * 3 + it;
        int r = gid >> 7, nb = gid & 127;
        int l = r / 6, m = r - l * 6;
        int n = nb * 4 + wave;
        const float* wrow = a.w[m] + (size_t)l * DD * DD + (size_t)n * DD;
        float4 w0 = *(const float4*)&wrow[lane * 8];
        float4 w1 = *(const float4*)&wrow[lane * 8 + 4];
        float we[8] = {w0.x, w0.y, w0.z, w0.w, w1.x, w1.y, w1.z, w1.w};
        bool folded = (m < 3) || (m == 4);
        float s1 = 0.f, sb = 0.f, wg[8];
        if (folded) {
            const float* gp = (m < 3) ? a.ln1_g + l * DD : a.ln2_g + l * DD;
            const float* bp = (m < 3) ? a.ln1_b + l * DD : a.ln2_b + l * DD;
            float4 g0 = *(const float4*)&gp[lane * 8];
            float4 g1 = *(const float4*)&gp[lane * 8 + 4];
            float4 b0 = *(const float4*)&bp[lane * 8];
            float4 b1 = *(const float4*)&bp[lane * 8 + 4];
            float ge[8] = {g0.x, g0.y, g0.z, g0.w, g1.x, g1.y, g1.z, g1.w};
            float be[8] = {b0.x, b0.y, b0.z, b0.w, b1.x, b1.y, b1.z, b1.w};
#pragma unroll
            for (int e = 0; e < 8; e++) { wg[e] = we[e] * ge[e]; s1 += wg[e]; sb += we[e] * be[e]; }
        } else {
#pragma unroll
            for (int e = 0; e < 8; e++) wg[e] = we[e];
        }
        ushort8 ov;
#pragma unroll
        for (int e = 0; e < 8; e++) ov[e] = f2bf(wg[e]);
        *(ushort8*)&a.wc[(size_t)r * DD * DD + (size_t)n * DD + lane * 8] = ov;
        if (folded) {
#pragma unroll
            for (int off = 32; off; off >>= 1) { s1 += __shfl_xor(s1, off); sb += __shfl_xor(sb, off); }
        }
        if (lane == 0) {
            a.c1[r * DD + n] = folded ? s1 : 0.f;
            a.c0[r * DD + n] = (folded ? sb : 0.f) + a.bias[m][l * DD + n];
        }
    }
    // --- build idx: 2 rows per wave
    if (t < 8) cbar[t] = 0;
    __syncthreads();
    for (int h = 0; h < 2; h++) {
        int rr = wave * 2 + h;
        int row = bid * 8 + rr;
        const int4* mr = (const int4*)(a.mask + (size_t)row * NN);
        for (int j4 = lane; j4 < NN / 4; j4 += 64) {
            int4 m4 = mr[j4];
            int base = j4 * 4;
            if (m4.x == 0) { int p = atomicAdd(&cbar[rr], 1); if (p < CAP) a.idx[row * CAP + p] = base; }
            if (m4.y == 0) { int p = atomicAdd(&cbar[rr], 1); if (p < CAP) a.idx[row * CAP + p] = base + 1; }
            if (m4.z == 0) { int p = atomicAdd(&cbar[rr], 1); if (p < CAP) a.idx[row * CAP + p] = base + 2; }
            if (m4.w == 0) { int p = atomicAdd(&cbar[rr], 1); if (p < CAP) a.idx[row * CAP + p] = base + 3; }
        }
    }
    __syncthreads();
    if (t < 8) { int c = cbar[t]; a.cnt[bid * 8 + t] = (c < CAP) ? c : CAP; }
    // --- init stats: wave per row, 2 iters
    for (int h = 0; h < 2; h++) {
        int row = bid * 8 + wave + h * 4;
        const float* xr = a.nfeat + (size_t)row * DD;
        float4 p0 = *(const float4*)&xr[lane * 8];
        float4 p1 = *(const float4*)&xr[lane * 8 + 4];
        float v[8] = {p0.x, p0.y, p0.z, p0.w, p1.x, p1.y, p1.z, p1.w};
        float s = 0.f, q = 0.f;
        ushort8 ov;
#pragma unroll
        for (int e = 0; e < 8; e++) { s += v[e]; q += v[e] * v[e]; ov[e] = f2bf(v[e]); }
#pragma unroll
        for (int off = 32; off; off >>= 1) { s += __shfl_xor(s, off); q += __shfl_xor(q, off); }
        *(ushort8*)&a.xb[(size_t)row * DD + lane * 8] = ov;
        if (lane == 0) { a.S0[2 * row] = s; a.S0[2 * row + 1] = q; }
    }
}

// GEMM tile body. K=512 fixed. MODE 0: LN-folded -> bf16; 1: +gelu; 2: residual->fp32+bf16+Spart; 3: residual->fp32 only
template <int MODE>
__device__ void gemm_body(const u16* __restrict__ A, const u16* __restrict__ B,
                          const float* __restrict__ c0, const float* __restrict__ c1,
                          const float* __restrict__ Sfin, const float* __restrict__ Ppart,
                          const float* __restrict__ resIn, float* __restrict__ resOut,
                          u16* __restrict__ outB, float* __restrict__ Ppout,
                          int bx, int by, int Nout, int t,
                          u16* As, u16* Bs, float* lnA, float* lnB, float (*ssc)[2][2]) {
    const int wave = t >> 6, lane = t & 63;
    const int m0 = by * 64, n0 = bx * 64;
    const int wm = (wave & 1) * 32, wn = (wave >> 1) * 32;
    const int srow = t >> 2, scol = (t & 3) * 8;
    const int fr = lane & 15, fq = (lane >> 4) * 8;

    if (MODE < 2) {
        if (t < 64) {
            int row = m0 + t;
            float s, q;
            if (Sfin) { s = Sfin[2 * row]; q = Sfin[2 * row + 1]; }
            else {
                s = 0.f; q = 0.f;
#pragma unroll
                for (int p = 0; p < 8; p++) {
                    s += Ppart[((size_t)p * NN + row) * 2];
                    q += Ppart[((size_t)p * NN + row) * 2 + 1];
                }
            }
            float mu = s * (1.0f / DD);
            float var = q * (1.0f / DD) - mu * mu;
            float rm = rsqrtf(var + 1e-5f);
            lnA[t] = rm; lnB[t] = rm * mu;
        }
    }

    floatx4 acc[2][2] = {};
    const u16* ag = A + (size_t)(m0 + srow) * DD + scol;
    const u16* bg = B + (size_t)(n0 + srow) * DD + scol;
    u16* as = As + t * 8;
    u16* bs = Bs + t * 8;

    for (int k0 = 0; k0 < DD; k0 += 32) {
        __syncthreads();
        gld_lds16(ag + k0, as);
        gld_lds16(bg + k0, bs);
        __syncthreads();
        short8 af[2], bf[2];
#pragma unroll
        for (int i = 0; i < 2; i++) af[i] = *(const short8*)&As[(wm + 16 * i + fr) * 32 + fq];
#pragma unroll
        for (int j = 0; j < 2; j++) bf[j] = *(const short8*)&Bs[(wn + 16 * j + fr) * 32 + fq];
#pragma unroll
        for (int i = 0; i < 2; i++)
#pragma unroll
            for (int j = 0; j < 2; j++)
                acc[i][j] = __builtin_amdgcn_mfma_f32_16x16x32_bf16(af[i], bf[j], acc[i][j], 0, 0, 0);
    }

    const int er = (lane >> 4) * 4, ec = lane & 15;
    int colj[2]; float c0v[2], c1v[2];
#pragma unroll
    for (int j = 0; j < 2; j++) {
        colj[j] = n0 + wn + 16 * j + ec;
        c0v[j] = c0[colj[j]];
        if (MODE < 2) c1v[j] = c1[colj[j]];
    }

#pragma unroll
    for (int i = 0; i < 2; i++) {
#pragma unroll
        for (int r = 0; r < 4; r++) {
            int rowL = wm + 16 * i + er + r;
            int row = m0 + rowL;
            if (MODE < 2) {
                float rm = lnA[rowL], rmu = lnB[rowL];
#pragma unroll
                for (int j = 0; j < 2; j++) {
                    float val = rm * acc[i][j][r] - rmu * c1v[j] + c0v[j];
                    if (MODE == 1) val = 0.5f * val * (1.0f + erff(val * 0.70710678118654752f));
                    outB[(size_t)row * Nout + colj[j]] = f2bf(val);
                }
            } else {
                float xn[2];
#pragma unroll
                for (int j = 0; j < 2; j++) {
                    xn[j] = resIn[(size_t)row * Nout + colj[j]] + acc[i][j][r] + c0v[j];
                    resOut[(size_t)row * Nout + colj[j]] = xn[j];
                    if (MODE == 2) outB[(size_t)row * Nout + colj[j]] = f2bf(xn[j]);
                }
                if (MODE == 2) {
                    float s = xn[0] + xn[1];
                    float q = xn[0] * xn[0] + xn[1] * xn[1];
#pragma unroll
                    for (int off = 1; off < 16; off <<= 1) { s += __shfl_xor(s, off); q += __shfl_xor(q, off); }
                    if ((lane & 15) == 0) { ssc[rowL][wn >> 5][0] = s; ssc[rowL][wn >> 5][1] = q; }
                }
            }
        }
    }
    if (MODE == 2) {
        __syncthreads();
        if (t < 64) {
            float s = ssc[t][0][0] + ssc[t][1][0];
            float q = ssc[t][0][1] + ssc[t][1][1];
            Ppout[((size_t)bx * NN + m0 + t) * 2] = s;
            Ppout[((size_t)bx * NN + m0 + t) * 2 + 1] = q;
        }
    }
}

// attention: 8 queries per block (2 qslots x 4 iters), 2 waves per query
__device__ void attn_body(const u16* __restrict__ qkv, const int* __restrict__ idx,
                          const int* __restrict__ cnt, u16* __restrict__ o,
                          int bid, int t, float (*obuf)[64][8], float (*sbuf)[64]) {
    const int wave = t >> 6, lane = t & 63;
    const int qslot = wave >> 1, half = wave & 1;
    for (int it = 0; it < 4; it++) {
        __syncthreads();
        int qi = bid * 8 + it * 2 + qslot;
        ushort8 qv = *(const ushort8*)(qkv + (size_t)qi * 1536 + lane * 8);
        float qf[8];
#pragma unroll
        for (int e = 0; e < 8; e++) qf[e] = bf2f(qv[e]);
        int c = cnt[qi];
        const int* ir = idx + qi * CAP;
        float sum = 0.f, oa[8] = {};
        for (int j = half; j < c; j += 2) {
            int kj = ir[j];
            const u16* kv_base = qkv + (size_t)kj * 1536;
            ushort8 kv = *(const ushort8*)(kv_base + 512 + lane * 8);
            ushort8 vv = *(const ushort8*)(kv_base + 1024 + lane * 8);
            float d = 0.f;
#pragma unroll
            for (int e = 0; e < 8; e++) d += qf[e] * bf2f(kv[e]);
            d += __shfl_xor(d, 1);
            d += __shfl_xor(d, 2);
            d += __shfl_xor(d, 4);
            d += __shfl_xor(d, 8);
            float p = __expf(d * SCALE);
            sum += p;
#pragma unroll
            for (int e = 0; e < 8; e++) oa[e] += p * bf2f(vv[e]);
        }
        if (half == 1) {
#pragma unroll
            for (int e = 0; e < 8; e++) obuf[qslot][lane][e] = oa[e];
            sbuf[qslot][lane] = sum;
        }
        __syncthreads();
        if (half == 0) {
            sum += sbuf[qslot][lane];
            float inv = 1.0f / sum;
            ushort8 ov;
#pragma unroll
            for (int e = 0; e < 8; e++) ov[e] = f2bf((oa[e] + obuf[qslot][lane][e]) * inv);
            *(ushort8*)(o + (size_t)qi * 512 + lane * 8) = ov;
        }
    }
}

// ================================================================ mega kernel (cooperative)
#define MEGA_SHARED \
    __shared__ u16 As[64 * 32]; \
    __shared__ u16 Bs[64 * 32]; \
    __shared__ float lnA[64], lnB[64]; \
    __shared__ float ssc[64][2][2]; \
    __shared__ float obuf[2][64][8]; \
    __shared__ float sbuf[2][64]; \
    __shared__ int cbar[8];

__launch_bounds__(256, 2)
__global__ void mega(KArgs a) {
    MEGA_SHARED
    cg::grid_group grid = cg::this_grid();
    const int bid = blockIdx.x, t = threadIdx.x;

    setup_body(a, bid, t, cbar);
    grid.sync();

    for (int l = 0; l < 2; l++) {
        const u16* wl = a.wc + (size_t)l * 6 * DD * DD;
        const float* cl0 = a.c0 + l * 6 * DD;
        const float* cl1 = a.c1 + l * 6 * DD;
        const float* Sfin = (l == 0) ? a.S0 : nullptr;

        // QKV: 3 tiles of the (24 x 64) grid
        for (int it = 0; it < 3; it++) {
            int tid2 = it * 512 + bid;
            int bx = tid2 % 24, by = tid2 / 24;
            __syncthreads();
            gemm_body<0>(a.xb, wl, cl0, cl1, Sfin, a.P, nullptr, nullptr, a.qkv, nullptr,
                         bx, by, 1536, t, As, Bs, lnA, lnB, ssc);
        }
        grid.sync();

        attn_body(a.qkv, a.idx, a.cnt, a.o, bid, t, obuf, sbuf);
        grid.sync();

        // o-proj + residual -> x, xb, partials
        gemm_body<2>(a.o, wl + (size_t)3 * DD * DD, cl0 + 3 * DD, nullptr, nullptr, nullptr,
                     (l == 0) ? a.nfeat : a.x, a.x, a.xb, a.P,
                     bid & 7, bid >> 3, DD, t, As, Bs, lnA, lnB, ssc);
        grid.sync();

        // fc1 (ln2-folded via partials) + gelu -> m1
        gemm_body<1>(a.xb, wl + (size_t)4 * DD * DD, cl0 + 4 * DD, cl1 + 4 * DD, nullptr, a.P,
                     nullptr, nullptr, a.m1, nullptr,
                     bid & 7, bid >> 3, FF, t, As, Bs, lnA, lnB, ssc);
        grid.sync();

        // fc2 + residual
        if (l == 0) {
            gemm_body<2>(a.m1, wl + (size_t)5 * DD * DD, cl0 + 5 * DD, nullptr, nullptr, nullptr,
                         a.x, a.x, a.xb, a.P,
                         bid & 7, bid >> 3, DD, t, As, Bs, lnA, lnB, ssc);
            grid.sync();
        } else {
            gemm_body<3>(a.m1, wl + (size_t)5 * DD * DD, cl0 + 5 * DD, nullptr, nullptr, nullptr,
                         a.x, a.out, nullptr, nullptr,
                         bid & 7, bid >> 3, DD, t, As, Bs, lnA, lnB, ssc);
        }
    }
}

// ================================================================ fallback wrappers
__launch_bounds__(256, 2)
__global__ void setup_kernel(KArgs a) {
    __shared__ int cbar[8];
    setup_body(a, blockIdx.x, threadIdx.x, cbar);
}

template <int MODE>
__launch_bounds__(256, 2)
__global__ void gemm_stage(const u16* A, const u16* B, const float* c0, const float* c1,
                           const float* Sfin, const float* Ppart, const float* resIn,
                           float* resOut, u16* outB, float* Ppout, int ntx, int Nout) {
    __shared__ u16 As[64 * 32];
    __shared__ u16 Bs[64 * 32];
    __shared__ float lnA[64], lnB[64];
    __shared__ float ssc[64][2][2];
    int bx = blockIdx.x % ntx, by = blockIdx.x / ntx;
    gemm_body<MODE>(A, B, c0, c1, Sfin, Ppart, resIn, resOut, outB, Ppout,
                    bx, by, Nout, threadIdx.x, As, Bs, lnA, lnB, ssc);
}

__launch_bounds__(256, 2)
__global__ void attn_stage(const u16* qkv, const int* idx, const int* cnt, u16* o) {
    __shared__ float obuf[2][64][8];
    __shared__ float sbuf[2][64];
    attn_body(qkv, idx, cnt, o, blockIdx.x, threadIdx.x, obuf, sbuf);
}

// ================================================================ launch
extern "C" void kernel_launch(void* const* d_in, const int* in_sizes, int n_in,
                              void* d_out, int out_size, void* d_ws, size_t ws_size,
                              hipStream_t stream) {
    KArgs a;
    a.nfeat = (const float*)d_in[0];
    a.mask  = (const int*)d_in[1];
    a.ln1_g = (const float*)d_in[2];
    a.ln1_b = (const float*)d_in[3];
    a.w[0] = (const float*)d_in[4];  a.bias[0] = (const float*)d_in[5];
    a.w[1] = (const float*)d_in[6];  a.bias[1] = (const float*)d_in[7];
    a.w[2] = (const float*)d_in[8];  a.bias[2] = (const float*)d_in[9];
    a.w[3] = (const float*)d_in[10]; a.bias[3] = (const float*)d_in[11];
    a.ln2_g = (const float*)d_in[12];
    a.ln2_b = (const float*)d_in[13];
    a.w[4] = (const float*)d_in[14]; a.bias[4] = (const float*)d_in[15];
    a.w[5] = (const float*)d_in[16]; a.bias[5] = (const float*)d_in[17];

    const size_t ND = (size_t)NN * DD;
    a.x   = (float*)d_ws;
    a.xb  = (u16*)(a.x + ND);
    a.qkv = a.xb + ND;
    a.o   = a.qkv + (size_t)NN * 1536;
    a.m1  = a.o + ND;
    a.wc  = a.m1 + ND;
    a.c0  = (float*)(a.wc + (size_t)12 * DD * DD);
    a.c1  = a.c0 + 12 * DD;
    a.S0  = a.c1 + 12 * DD;
    a.P   = a.S0 + (size_t)NN * 2;
    a.idx = (int*)(a.P + (size_t)8 * NN * 2);
    a.cnt = a.idx + (size_t)NN * CAP;
    a.out = (float*)d_out;

    void* params[] = {(void*)&a};
    hipError_t err = hipLaunchCooperativeKernel((const void*)mega, dim3(512), dim3(256),
                                                params, 0, stream);
    if (err != hipSuccess) {
        // fallback: equivalent multi-kernel sequence (same device bodies)
        setup_kernel<<<512, 256, 0, stream>>>(a);
        for (int l = 0; l < 2; l++) {
            const u16* wl = a.wc + (size_t)l * 6 * DD * DD;
            const float* cl0 = a.c0 + l * 6 * DD;
            const float* cl1 = a.c1 + l * 6 * DD;
            const float* Sfin = (l == 0) ? a.S0 : nullptr;
            gemm_stage<0><<<1536, 256, 0, stream>>>(a.xb, wl, cl0, cl1, Sfin, a.P,
                                                    nullptr, nullptr, a.qkv, nullptr, 24, 1536);
            attn_stage<<<512, 256, 0, stream>>>(a.qkv, a.idx, a.cnt, a.o);
            gemm_stage<2><<<512, 256, 0, stream>>>(a.o, wl + (size_t)3 * DD * DD, cl0 + 3 * DD, nullptr,
                                                   nullptr, nullptr, (l == 0) ? a.nfeat : a.x,
                                                   a.x, a.xb, a.P, 8, DD);
            gemm_stage<1><<<512, 256, 0, stream>>>(a.xb, wl + (size_t)4 * DD * DD, cl0 + 4 * DD, cl1 + 4 * DD,
                                                   nullptr, a.P, nullptr, nullptr, a.m1, nullptr, 8, FF);
            if (l == 0) {
                gemm_stage<2><<<512, 256, 0, stream>>>(a.m1, wl + (size_t)5 * DD * DD, cl0 + 5 * DD, nullptr,
                                                       nullptr, nullptr, a.x, a.x, a.xb, a.P, 8, DD);
            } else {
                gemm_stage<3><<<512, 256, 0, stream>>>(a.m1, wl + (size_t)5 * DD * DD, cl0 + 5 * DD, nullptr,
                                                       nullptr, nullptr, a.x, a.out, nullptr, nullptr, 8, DD);
            }
        }
    }
}

// Round 6
// 343.066 us; speedup vs baseline: 2.9205x; 2.9205x over previous
//
#include <hip/hip_runtime.h>
#include <math.h>

#define NN 4096
#define DD 512
#define FF 512
#define CAP 256
#define SCALE 0.08838834764831845f

typedef unsigned short u16;
typedef __attribute__((ext_vector_type(8))) short short8;
typedef __attribute__((ext_vector_type(8))) unsigned short ushort8;
typedef __attribute__((ext_vector_type(4))) unsigned short ushort4v;
typedef __attribute__((ext_vector_type(4))) float floatx4;

__device__ __forceinline__ float bf2f(u16 u) {
    union { unsigned int i; float f; } x; x.i = ((unsigned int)u) << 16; return x.f;
}
__device__ __forceinline__ u16 f2bf(float f) {
    union { float f; unsigned int i; } x; x.f = f;
    unsigned int r = (x.i + 0x7FFFu + ((x.i >> 16) & 1u)) >> 16;
    return (u16)r;
}
__device__ __forceinline__ void gld_lds16(const void* g, void* l) {
    __builtin_amdgcn_global_load_lds((const __attribute__((address_space(1))) void*)g,
                                     (__attribute__((address_space(3))) void*)l, 16, 0, 0);
}

// ---------------------------------------------------------------- setup: cast weights + bias concat + idx build
struct SetupArgs {
    const float* w[6];
    const float* bq; const float* bk; const float* bv;
    const int* mask;
    u16* wc; float* bcat; int* idx; int* cnt;
};
__global__ void setup_kernel(SetupArgs a) {
    const int bid = blockIdx.x, t = threadIdx.x;
    const int wave = t >> 6, lane = t & 63;
    __shared__ int cbar[8];

    // --- cast 12 fp32 512x512 matrices to bf16: 3 row-groups of 4 rows per block
    for (int it = 0; it < 3; it++) {
        int gid = bid * 3 + it;                 // 0..1535
        int r = gid >> 7, nb = gid & 127;       // region 0..11
        int l = r / 6, m = r - l * 6;
        int n = nb * 4 + wave;
        const float* src = a.w[m] + (size_t)l * DD * DD + (size_t)n * DD;
        float4 w0 = *(const float4*)&src[lane * 8];
        float4 w1 = *(const float4*)&src[lane * 8 + 4];
        float we[8] = {w0.x, w0.y, w0.z, w0.w, w1.x, w1.y, w1.z, w1.w};
        ushort8 ov;
#pragma unroll
        for (int e = 0; e < 8; e++) ov[e] = f2bf(we[e]);
        *(ushort8*)&a.wc[(size_t)r * DD * DD + (size_t)n * DD + lane * 8] = ov;
    }

    // --- bias concat (block 0)
    if (bid == 0) {
        for (int l = 0; l < 2; l++)
            for (int it = 0; it < 6; it++) {
                int j = it * 256 + t;           // 0..1535
                int m = j >> 9, col = j & 511;
                const float* bp = (m == 0) ? a.bq : (m == 1) ? a.bk : a.bv;
                a.bcat[l * 1536 + j] = bp[l * DD + col];
            }
    }

    // --- idx build: 8 rows per block, 2 rows per wave
    if (t < 8) cbar[t] = 0;
    __syncthreads();
    for (int h = 0; h < 2; h++) {
        int rr = wave * 2 + h;
        int row = bid * 8 + rr;
        const int4* mr = (const int4*)(a.mask + (size_t)row * NN);
        for (int j4 = lane; j4 < NN / 4; j4 += 64) {
            int4 m4 = mr[j4];
            int base = j4 * 4;
            if (m4.x == 0) { int p = atomicAdd(&cbar[rr], 1); if (p < CAP) a.idx[row * CAP + p] = base; }
            if (m4.y == 0) { int p = atomicAdd(&cbar[rr], 1); if (p < CAP) a.idx[row * CAP + p] = base + 1; }
            if (m4.z == 0) { int p = atomicAdd(&cbar[rr], 1); if (p < CAP) a.idx[row * CAP + p] = base + 2; }
            if (m4.w == 0) { int p = atomicAdd(&cbar[rr], 1); if (p < CAP) a.idx[row * CAP + p] = base + 3; }
        }
    }
    __syncthreads();
    if (t < 8) { int c = cbar[t]; a.cnt[bid * 8 + t] = (c < CAP) ? c : CAP; }
}

// ---------------------------------------------------------------- layernorm (fp32 in, bf16 out)
__global__ void ln_kernel(const float* __restrict__ x, const float* __restrict__ g,
                          const float* __restrict__ b, u16* __restrict__ out) {
    int wave = threadIdx.x >> 6, lane = threadIdx.x & 63;
    int row = blockIdx.x * 4 + wave;
    const float* xr = x + (size_t)row * DD;
    float4 p0 = *(const float4*)&xr[lane * 8];
    float4 p1 = *(const float4*)&xr[lane * 8 + 4];
    float v[8] = {p0.x, p0.y, p0.z, p0.w, p1.x, p1.y, p1.z, p1.w};
    float s = 0.f;
#pragma unroll
    for (int i = 0; i < 8; i++) s += v[i];
#pragma unroll
    for (int off = 32; off; off >>= 1) s += __shfl_xor(s, off);
    float mu = s * (1.0f / DD);
    float vs = 0.f;
#pragma unroll
    for (int i = 0; i < 8; i++) { float d = v[i] - mu; vs += d * d; }
#pragma unroll
    for (int off = 32; off; off >>= 1) vs += __shfl_xor(vs, off);
    float r = rsqrtf(vs * (1.0f / DD) + 1e-5f);
    float4 g0 = *(const float4*)&g[lane * 8];
    float4 g1 = *(const float4*)&g[lane * 8 + 4];
    float4 b0 = *(const float4*)&b[lane * 8];
    float4 b1 = *(const float4*)&b[lane * 8 + 4];
    float ge[8] = {g0.x, g0.y, g0.z, g0.w, g1.x, g1.y, g1.z, g1.w};
    float be[8] = {b0.x, b0.y, b0.z, b0.w, b1.x, b1.y, b1.z, b1.w};
    ushort8 ov;
#pragma unroll
    for (int i = 0; i < 8; i++) ov[i] = f2bf((v[i] - mu) * r * ge[i] + be[i]);
    *(ushort8*)&out[(size_t)row * DD + lane * 8] = ov;
}

// ---------------------------------------------------------------- bf16 MFMA GEMM, 128xTN tile (TN = NJ*32)
// C[4096, Nout] = A[4096,512] @ B[Nout,512]^T + bias
// MODE 0: -> bf16; 1: gelu -> bf16; 2: resOut = resIn + val (fp32)
template <int MODE, int NJ>
__launch_bounds__(256)
__global__ void gemm_bf16(const u16* __restrict__ A, const u16* __restrict__ B,
                          const float* __restrict__ bias, const float* __restrict__ resIn,
                          float* __restrict__ resOut, u16* __restrict__ outB, int Nout) {
    constexpr int TN = NJ * 32;
    __shared__ u16 As[128 * 32];
    __shared__ u16 Bs[TN * 32];
    const int m0 = blockIdx.y * 128, n0 = blockIdx.x * TN;
    const int t = threadIdx.x;
    const int wave = t >> 6, lane = t & 63;
    const int wm = (wave & 1) * 64, wn = (wave >> 1) * (TN / 2);
    const int srow = t >> 2, scol = (t & 3) * 8;
    const int fr = lane & 15, fq = (lane >> 4) * 8;

    floatx4 acc[4][NJ] = {};

    const u16* ag0 = A + (size_t)(m0 + srow) * DD + scol;
    const u16* ag1 = ag0 + (size_t)64 * DD;
    const u16* bg0 = B + (size_t)(n0 + srow) * DD + scol;
    const u16* bg1 = bg0 + (size_t)64 * DD;
    u16* as0 = As + t * 8;
    u16* as1 = as0 + 64 * 32;
    u16* bs0 = Bs + t * 8;
    u16* bs1 = bs0 + 64 * 32;

    for (int k0 = 0; k0 < DD; k0 += 32) {
        __syncthreads();
        gld_lds16(ag0 + k0, as0);
        gld_lds16(ag1 + k0, as1);
        gld_lds16(bg0 + k0, bs0);
        if (NJ == 4) gld_lds16(bg1 + k0, bs1);
        __syncthreads();
        short8 af[4], bf[NJ];
#pragma unroll
        for (int i = 0; i < 4; i++)
            af[i] = *(const short8*)&As[(wm + 16 * i + fr) * 32 + fq];
#pragma unroll
        for (int j = 0; j < NJ; j++)
            bf[j] = *(const short8*)&Bs[(wn + 16 * j + fr) * 32 + fq];
#pragma unroll
        for (int i = 0; i < 4; i++)
#pragma unroll
            for (int j = 0; j < NJ; j++)
                acc[i][j] = __builtin_amdgcn_mfma_f32_16x16x32_bf16(af[i], bf[j], acc[i][j], 0, 0, 0);
    }

    const int er = (lane >> 4) * 4, ec = lane & 15;
    int colj[NJ]; float bv[NJ];
#pragma unroll
    for (int j = 0; j < NJ; j++) {
        colj[j] = n0 + wn + 16 * j + ec;
        bv[j] = bias[colj[j]];
    }
#pragma unroll
    for (int i = 0; i < 4; i++) {
#pragma unroll
        for (int r = 0; r < 4; r++) {
            int row = m0 + wm + 16 * i + er + r;
#pragma unroll
            for (int j = 0; j < NJ; j++) {
                float val = acc[i][j][r] + bv[j];
                if (MODE == 1) val = 0.5f * val * (1.0f + erff(val * 0.70710678118654752f));
                if (MODE == 2) {
                    resOut[(size_t)row * Nout + colj[j]] = resIn[(size_t)row * Nout + colj[j]] + val;
                } else {
                    outB[(size_t)row * Nout + colj[j]] = f2bf(val);
                }
            }
        }
    }
}

// ---------------------------------------------------------------- sparse attention
// single-pass (|scores| small), 2 waves per query, 4 queries/block (512 thr)
__global__ void sparse_attn(const u16* __restrict__ qkv, const int* __restrict__ idx,
                            const int* __restrict__ cnt, u16* __restrict__ o) {
    int wave = threadIdx.x >> 6, lane = threadIdx.x & 63;
    int qslot = wave >> 1, half = wave & 1;
    int qi = blockIdx.x * 4 + qslot;
    __shared__ float obuf[4][64][8];
    __shared__ float sbuf[4][64];

    ushort8 qv = *(const ushort8*)(qkv + (size_t)qi * 1536 + lane * 8);
    float qf[8];
#pragma unroll
    for (int e = 0; e < 8; e++) qf[e] = bf2f(qv[e]);

    int c = cnt[qi];
    const int* ir = idx + qi * CAP;
    float sum = 0.f, oa[8] = {};

    for (int j = half; j < c; j += 2) {
        int kj = ir[j];
        const u16* kv_base = qkv + (size_t)kj * 1536;
        ushort8 kv = *(const ushort8*)(kv_base + 512 + lane * 8);
        ushort8 vv = *(const ushort8*)(kv_base + 1024 + lane * 8);
        float d = 0.f;
#pragma unroll
        for (int e = 0; e < 8; e++) d += qf[e] * bf2f(kv[e]);
        d += __shfl_xor(d, 1);
        d += __shfl_xor(d, 2);
        d += __shfl_xor(d, 4);
        d += __shfl_xor(d, 8);
        float p = __expf(d * SCALE);
        sum += p;
#pragma unroll
        for (int e = 0; e < 8; e++) oa[e] += p * bf2f(vv[e]);
    }

    if (half == 1) {
#pragma unroll
        for (int e = 0; e < 8; e++) obuf[qslot][lane][e] = oa[e];
        sbuf[qslot][lane] = sum;
    }
    __syncthreads();
    if (half == 0) {
        sum += sbuf[qslot][lane];
        float inv = 1.0f / sum;
        ushort8 ov;
#pragma unroll
        for (int e = 0; e < 8; e++) ov[e] = f2bf((oa[e] + obuf[qslot][lane][e]) * inv);
        *(ushort8*)(o + (size_t)qi * 512 + lane * 8) = ov;
    }
}

// ---------------------------------------------------------------- launch
extern "C" void kernel_launch(void* const* d_in, const int* in_sizes, int n_in,
                              void* d_out, int out_size, void* d_ws, size_t ws_size,
                              hipStream_t stream) {
    const float* nfeat = (const float*)d_in[0];
    const int*   mask  = (const int*)d_in[1];
    const float* ln1_g = (const float*)d_in[2];
    const float* ln1_b = (const float*)d_in[3];
    const float* bo    = (const float*)d_in[11];
    const float* ln2_g = (const float*)d_in[12];
    const float* ln2_b = (const float*)d_in[13];
    const float* fc1_b = (const float*)d_in[15];
    const float* fc2_b = (const float*)d_in[17];

    const size_t ND = (size_t)NN * DD;
    float* x   = (float*)d_ws;                       // 8 MB
    u16*   h   = (u16*)(x + ND);                     // 4 MB
    u16*   qkv = h + ND;                             // 12 MB
    u16*   o   = qkv + (size_t)NN * 1536;            // 4 MB
    u16*   m1  = o + ND;                             // 4 MB
    u16*   wc  = m1 + ND;                            // 6 MB
    float* bcat = (float*)(wc + (size_t)12 * DD * DD);
    int*   idx  = (int*)(bcat + 2 * 1536);           // 4 MB
    int*   cnt  = idx + (size_t)NN * CAP;

    SetupArgs sa;
    sa.w[0] = (const float*)d_in[4];  sa.w[1] = (const float*)d_in[6];
    sa.w[2] = (const float*)d_in[8];  sa.w[3] = (const float*)d_in[10];
    sa.w[4] = (const float*)d_in[14]; sa.w[5] = (const float*)d_in[16];
    sa.bq = (const float*)d_in[5]; sa.bk = (const float*)d_in[7]; sa.bv = (const float*)d_in[9];
    sa.mask = mask; sa.wc = wc; sa.bcat = bcat; sa.idx = idx; sa.cnt = cnt;

    setup_kernel<<<512, 256, 0, stream>>>(sa);

    const size_t SS = (size_t)DD * DD;
    for (int l = 0; l < 2; l++) {
        size_t bOff = (size_t)l * DD;
        u16* wl = wc + (size_t)l * 6 * SS;
        const float* xin = (l == 0) ? nfeat : x;
        float* fc2_dst = (l == 1) ? (float*)d_out : x;

        ln_kernel<<<NN / 4, 256, 0, stream>>>(xin, ln1_g + bOff, ln1_b + bOff, h);
        gemm_bf16<0, 4><<<dim3(12, 32), 256, 0, stream>>>(h, wl, bcat + l * 1536,
                                                          nullptr, nullptr, qkv, 1536);
        sparse_attn<<<NN / 4, 512, 0, stream>>>(qkv, idx, cnt, o);
        gemm_bf16<2, 2><<<dim3(8, 32), 256, 0, stream>>>(o, wl + 3 * SS, bo + bOff,
                                                         xin, x, nullptr, DD);
        ln_kernel<<<NN / 4, 256, 0, stream>>>(x, ln2_g + bOff, ln2_b + bOff, h);
        gemm_bf16<1, 2><<<dim3(8, 32), 256, 0, stream>>>(h, wl + 4 * SS, fc1_b + bOff,
                                                         nullptr, nullptr, m1, FF);
        gemm_bf16<2, 2><<<dim3(8, 32), 256, 0, stream>>>(m1, wl + 5 * SS, fc2_b + bOff,
                                                         x, fc2_dst, nullptr, DD);
    }
}

// Round 7
// 293.647 us; speedup vs baseline: 3.4121x; 1.1683x over previous
//
#include <hip/hip_runtime.h>
#include <math.h>

#define NN 4096
#define DD 512
#define FF 512
#define CAP 256
#define SCALE 0.08838834764831845f

typedef unsigned short u16;
typedef __attribute__((ext_vector_type(8))) short short8;
typedef __attribute__((ext_vector_type(8))) unsigned short ushort8;
typedef __attribute__((ext_vector_type(4))) unsigned short ushort4v;
typedef __attribute__((ext_vector_type(4))) float floatx4;

__device__ __forceinline__ float bf2f(u16 u) {
    union { unsigned int i; float f; } x; x.i = ((unsigned int)u) << 16; return x.f;
}
__device__ __forceinline__ u16 f2bf(float f) {
    union { float f; unsigned int i; } x; x.f = f;
    unsigned int r = (x.i + 0x7FFFu + ((x.i >> 16) & 1u)) >> 16;
    return (u16)r;
}
__device__ __forceinline__ void gld_lds16(const void* g, void* l) {
    __builtin_amdgcn_global_load_lds((const __attribute__((address_space(1))) void*)g,
                                     (__attribute__((address_space(3))) void*)l, 16, 0, 0);
}

// ---------------------------------------------------------------- mask -> idx (R3-proven, 4096 blocks)
__global__ void build_idx_kernel(const int* __restrict__ mask,
                                 int* __restrict__ idx, int* __restrict__ cnt) {
    int row = blockIdx.x;
    __shared__ int c;
    if (threadIdx.x == 0) c = 0;
    __syncthreads();
    const int4* mrow = (const int4*)(mask + (size_t)row * NN);
    for (int j4 = threadIdx.x; j4 < NN / 4; j4 += blockDim.x) {
        int4 m4 = mrow[j4];
        int base = j4 * 4;
        if (m4.x == 0) idx[row * CAP + atomicAdd(&c, 1)] = base;
        if (m4.y == 0) idx[row * CAP + atomicAdd(&c, 1)] = base + 1;
        if (m4.z == 0) idx[row * CAP + atomicAdd(&c, 1)] = base + 2;
        if (m4.w == 0) idx[row * CAP + atomicAdd(&c, 1)] = base + 3;
    }
    __syncthreads();
    if (threadIdx.x == 0) cnt[row] = (c < CAP) ? c : CAP;
}

// ---------------------------------------------------------------- weights fp32 -> bf16 (R3-proven)
struct W6 { const float* w[6]; };
__global__ void cast_weights(W6 wp, u16* __restrict__ dst) {
    int region = blockIdx.x >> 4;
    int layer = region / 6, mat = region - layer * 6;
    const float* src = wp.w[mat] + (size_t)layer * (DD * DD);
    u16* d = dst + (size_t)region * (DD * DD);
    int off = (blockIdx.x & 15) * 16384 + threadIdx.x * 4;
#pragma unroll
    for (int i = 0; i < 16; i++) {
        int e = off + i * 1024;
        float4 f = *(const float4*)&src[e];
        ushort4v u;
        u.x = f2bf(f.x); u.y = f2bf(f.y); u.z = f2bf(f.z); u.w = f2bf(f.w);
        *(ushort4v*)&d[e] = u;
    }
}

__global__ void concat_bias(const float* __restrict__ bq, const float* __restrict__ bk,
                            const float* __restrict__ bv, float* __restrict__ bcat) {
    int l = blockIdx.x, t = threadIdx.x;
    bcat[l * 1536 + t]        = bq[l * 512 + t];
    bcat[l * 1536 + 512 + t]  = bk[l * 512 + t];
    bcat[l * 1536 + 1024 + t] = bv[l * 512 + t];
}

// ---------------------------------------------------------------- layernorm (fp32 in, bf16 out)
__global__ void ln_kernel(const float* __restrict__ x, const float* __restrict__ g,
                          const float* __restrict__ b, u16* __restrict__ out) {
    int wave = threadIdx.x >> 6, lane = threadIdx.x & 63;
    int row = blockIdx.x * 4 + wave;
    const float* xr = x + (size_t)row * DD;
    float4 p0 = *(const float4*)&xr[lane * 8];
    float4 p1 = *(const float4*)&xr[lane * 8 + 4];
    float v[8] = {p0.x, p0.y, p0.z, p0.w, p1.x, p1.y, p1.z, p1.w};
    float s = 0.f;
#pragma unroll
    for (int i = 0; i < 8; i++) s += v[i];
#pragma unroll
    for (int off = 32; off; off >>= 1) s += __shfl_xor(s, off);
    float mu = s * (1.0f / DD);
    float vs = 0.f;
#pragma unroll
    for (int i = 0; i < 8; i++) { float d = v[i] - mu; vs += d * d; }
#pragma unroll
    for (int off = 32; off; off >>= 1) vs += __shfl_xor(vs, off);
    float r = rsqrtf(vs * (1.0f / DD) + 1e-5f);
    float4 g0 = *(const float4*)&g[lane * 8];
    float4 g1 = *(const float4*)&g[lane * 8 + 4];
    float4 b0 = *(const float4*)&b[lane * 8];
    float4 b1 = *(const float4*)&b[lane * 8 + 4];
    float ge[8] = {g0.x, g0.y, g0.z, g0.w, g1.x, g1.y, g1.z, g1.w};
    float be[8] = {b0.x, b0.y, b0.z, b0.w, b1.x, b1.y, b1.z, b1.w};
    ushort8 ov;
#pragma unroll
    for (int i = 0; i < 8; i++) ov[i] = f2bf((v[i] - mu) * r * ge[i] + be[i]);
    *(ushort8*)&out[(size_t)row * DD + lane * 8] = ov;
}

// ---------------------------------------------------------------- 64x64 GEMM (R3-proven)
// MODE 0: -> bf16; 1: gelu -> bf16; 2: resOut = resIn + val (fp32)
template <int MODE>
__launch_bounds__(256)
__global__ void gemm_bf16(const u16* __restrict__ A, const u16* __restrict__ B,
                          const float* __restrict__ bias, const float* __restrict__ resIn,
                          float* __restrict__ resOut, u16* __restrict__ outB,
                          int M, int Nout, int K) {
    __shared__ u16 As[64 * 32];
    __shared__ u16 Bs[64 * 32];
    const int m0 = blockIdx.y * 64, n0 = blockIdx.x * 64;
    const int t = threadIdx.x;
    const int wave = t >> 6, lane = t & 63;
    const int wm = (wave & 1) * 32, wn = (wave >> 1) * 32;
    const int srow = t >> 2, scol = (t & 3) * 8;
    const int fr = lane & 15, fq = (lane >> 4) * 8;

    floatx4 acc[2][2] = {};
    const u16* ag = A + (size_t)(m0 + srow) * K + scol;
    const u16* bg = B + (size_t)(n0 + srow) * K + scol;
    u16* as = As + t * 8;
    u16* bs = Bs + t * 8;

    for (int k0 = 0; k0 < K; k0 += 32) {
        __syncthreads();
        gld_lds16(ag + k0, as);
        gld_lds16(bg + k0, bs);
        __syncthreads();
        short8 af[2], bf[2];
#pragma unroll
        for (int i = 0; i < 2; i++) af[i] = *(const short8*)&As[(wm + 16 * i + fr) * 32 + fq];
#pragma unroll
        for (int j = 0; j < 2; j++) bf[j] = *(const short8*)&Bs[(wn + 16 * j + fr) * 32 + fq];
#pragma unroll
        for (int i = 0; i < 2; i++)
#pragma unroll
            for (int j = 0; j < 2; j++)
                acc[i][j] = __builtin_amdgcn_mfma_f32_16x16x32_bf16(af[i], bf[j], acc[i][j], 0, 0, 0);
    }

    const int er = (lane >> 4) * 4, ec = lane & 15;
#pragma unroll
    for (int i = 0; i < 2; i++) {
#pragma unroll
        for (int j = 0; j < 2; j++) {
            int col = n0 + wn + 16 * j + ec;
            float bsv = bias[col];
#pragma unroll
            for (int r = 0; r < 4; r++) {
                int row = m0 + wm + 16 * i + er + r;
                float val = acc[i][j][r] + bsv;
                if (MODE == 1) val = 0.5f * val * (1.0f + erff(val * 0.70710678118654752f));
                if (MODE == 2) {
                    resOut[(size_t)row * Nout + col] = resIn[(size_t)row * Nout + col] + val;
                } else {
                    outB[(size_t)row * Nout + col] = f2bf(val);
                }
            }
        }
    }
}

// ---------------------------------------------------------------- 128x64 QKV GEMM (bias -> bf16)
// grid (24, 32): 768 blocks. 8 MFMA per 3 staging-glds per k-step.
__launch_bounds__(256)
__global__ void gemm_qkv(const u16* __restrict__ A, const u16* __restrict__ B,
                         const float* __restrict__ bias, u16* __restrict__ outB) {
    __shared__ u16 As[128 * 32];
    __shared__ u16 Bs[64 * 32];
    const int m0 = blockIdx.y * 128, n0 = blockIdx.x * 64;
    const int t = threadIdx.x;
    const int wave = t >> 6, lane = t & 63;
    const int wm = (wave & 1) * 64, wn = (wave >> 1) * 32;
    const int srow = t >> 2, scol = (t & 3) * 8;
    const int fr = lane & 15, fq = (lane >> 4) * 8;

    floatx4 acc[4][2] = {};
    const u16* ag0 = A + (size_t)(m0 + srow) * DD + scol;
    const u16* ag1 = ag0 + (size_t)64 * DD;
    const u16* bg = B + (size_t)(n0 + srow) * DD + scol;
    u16* as0 = As + t * 8;
    u16* as1 = as0 + 64 * 32;
    u16* bs = Bs + t * 8;

    for (int k0 = 0; k0 < DD; k0 += 32) {
        __syncthreads();
        gld_lds16(ag0 + k0, as0);
        gld_lds16(ag1 + k0, as1);
        gld_lds16(bg + k0, bs);
        __syncthreads();
        short8 af[4], bf[2];
#pragma unroll
        for (int i = 0; i < 4; i++) af[i] = *(const short8*)&As[(wm + 16 * i + fr) * 32 + fq];
#pragma unroll
        for (int j = 0; j < 2; j++) bf[j] = *(const short8*)&Bs[(wn + 16 * j + fr) * 32 + fq];
#pragma unroll
        for (int i = 0; i < 4; i++)
#pragma unroll
            for (int j = 0; j < 2; j++)
                acc[i][j] = __builtin_amdgcn_mfma_f32_16x16x32_bf16(af[i], bf[j], acc[i][j], 0, 0, 0);
    }

    const int er = (lane >> 4) * 4, ec = lane & 15;
#pragma unroll
    for (int j = 0; j < 2; j++) {
        int col = n0 + wn + 16 * j + ec;
        float bsv = bias[col];
#pragma unroll
        for (int i = 0; i < 4; i++) {
#pragma unroll
            for (int r = 0; r < 4; r++) {
                int row = m0 + wm + 16 * i + er + r;
                outB[(size_t)row * 1536 + col] = f2bf(acc[i][j][r] + bsv);
            }
        }
    }
}

// ---------------------------------------------------------------- sparse attention
// 2 waves/query, 4 queries/block; idx list staged to LDS; 2-deep K/V load pipeline
__global__ void sparse_attn(const u16* __restrict__ qkv, const int* __restrict__ idx,
                            const int* __restrict__ cnt, u16* __restrict__ o) {
    int t = threadIdx.x;
    int wave = t >> 6, lane = t & 63;
    int qslot = wave >> 1, half = wave & 1;
    int qi = blockIdx.x * 4 + qslot;
    __shared__ float obuf[4][64][8];
    __shared__ float sbuf[4][64];
    __shared__ int sidx[4][CAP];

    int c = cnt[qi];
    // stage idx list: 128 threads (2 waves) per query slot
    const int* ir = idx + qi * CAP;
    for (int j = t & 127; j < c; j += 128) sidx[qslot][j] = ir[j];

    ushort8 qv = *(const ushort8*)(qkv + (size_t)qi * 1536 + lane * 8);
    float qf[8];
#pragma unroll
    for (int e = 0; e < 8; e++) qf[e] = bf2f(qv[e]);
    __syncthreads();

    float sum = 0.f, oa[8] = {};
    int j = half;
    ushort8 kv, vv;
    if (j < c) {
        const u16* kb = qkv + (size_t)sidx[qslot][j] * 1536;
        kv = *(const ushort8*)(kb + 512 + lane * 8);
        vv = *(const ushort8*)(kb + 1024 + lane * 8);
    }
    while (j < c) {
        int jn = j + 2;
        ushort8 kvn, vvn;
        {   // issue next loads before consuming current (SW pipeline)
            int kjn = (jn < c) ? sidx[qslot][jn] : 0;
            const u16* nb = qkv + (size_t)kjn * 1536;
            kvn = *(const ushort8*)(nb + 512 + lane * 8);
            vvn = *(const ushort8*)(nb + 1024 + lane * 8);
        }
        float d = 0.f;
#pragma unroll
        for (int e = 0; e < 8; e++) d += qf[e] * bf2f(kv[e]);
        d += __shfl_xor(d, 1);
        d += __shfl_xor(d, 2);
        d += __shfl_xor(d, 4);
        d += __shfl_xor(d, 8);
        float p = __expf(d * SCALE);
        sum += p;
#pragma unroll
        for (int e = 0; e < 8; e++) oa[e] += p * bf2f(vv[e]);
        kv = kvn; vv = vvn;
        j = jn;
    }

    if (half == 1) {
#pragma unroll
        for (int e = 0; e < 8; e++) obuf[qslot][lane][e] = oa[e];
        sbuf[qslot][lane] = sum;
    }
    __syncthreads();
    if (half == 0) {
        sum += sbuf[qslot][lane];
        float inv = 1.0f / sum;
        ushort8 ov;
#pragma unroll
        for (int e = 0; e < 8; e++) ov[e] = f2bf((oa[e] + obuf[qslot][lane][e]) * inv);
        *(ushort8*)(o + (size_t)qi * 512 + lane * 8) = ov;
    }
}

// ---------------------------------------------------------------- launch
extern "C" void kernel_launch(void* const* d_in, const int* in_sizes, int n_in,
                              void* d_out, int out_size, void* d_ws, size_t ws_size,
                              hipStream_t stream) {
    const float* nfeat = (const float*)d_in[0];
    const int*   mask  = (const int*)d_in[1];
    const float* ln1_g = (const float*)d_in[2];
    const float* ln1_b = (const float*)d_in[3];
    const float* bo    = (const float*)d_in[11];
    const float* ln2_g = (const float*)d_in[12];
    const float* ln2_b = (const float*)d_in[13];
    const float* fc1_b = (const float*)d_in[15];
    const float* fc2_b = (const float*)d_in[17];

    const size_t ND = (size_t)NN * DD;
    float* x    = (float*)d_ws;                      // 8 MB
    u16*   h    = (u16*)(x + ND);                    // 4 MB
    u16*   qkv  = h + ND;                            // 12 MB
    u16*   o    = qkv + (size_t)NN * 1536;           // 4 MB
    u16*   m1   = o + ND;                            // 4 MB
    u16*   wc   = m1 + ND;                           // 12 MB
    float* bcat = (float*)(wc + (size_t)12 * DD * DD);
    int*   idx  = (int*)(bcat + 2 * 1536);           // 4 MB
    int*   cnt  = idx + (size_t)NN * CAP;

    W6 w6;
    w6.w[0] = (const float*)d_in[4];  w6.w[1] = (const float*)d_in[6];
    w6.w[2] = (const float*)d_in[8];  w6.w[3] = (const float*)d_in[10];
    w6.w[4] = (const float*)d_in[14]; w6.w[5] = (const float*)d_in[16];
    cast_weights<<<192, 256, 0, stream>>>(w6, wc);
    concat_bias<<<2, 512, 0, stream>>>((const float*)d_in[5], (const float*)d_in[7],
                                       (const float*)d_in[9], bcat);
    build_idx_kernel<<<NN, 256, 0, stream>>>(mask, idx, cnt);

    const size_t SS = (size_t)DD * DD;
    for (int l = 0; l < 2; l++) {
        size_t bOff = (size_t)l * DD;
        u16* wl = wc + (size_t)l * 6 * SS;
        const float* xin = (l == 0) ? nfeat : x;
        float* fc2_dst = (l == 1) ? (float*)d_out : x;

        ln_kernel<<<NN / 4, 256, 0, stream>>>(xin, ln1_g + bOff, ln1_b + bOff, h);
        gemm_qkv<<<dim3(24, 32), 256, 0, stream>>>(h, wl, bcat + l * 1536, qkv);
        sparse_attn<<<NN / 4, 512, 0, stream>>>(qkv, idx, cnt, o);
        gemm_bf16<2><<<dim3(8, 64), 256, 0, stream>>>(o, wl + 3 * SS, bo + bOff,
                                                      xin, x, nullptr, NN, DD, DD);
        ln_kernel<<<NN / 4, 256, 0, stream>>>(x, ln2_g + bOff, ln2_b + bOff, h);
        gemm_bf16<1><<<dim3(8, 64), 256, 0, stream>>>(h, wl + 4 * SS, fc1_b + bOff,
                                                      nullptr, nullptr, m1, NN, FF, DD);
        gemm_bf16<2><<<dim3(8, 64), 256, 0, stream>>>(m1, wl + 5 * SS, fc2_b + bOff,
                                                      x, fc2_dst, nullptr, NN, DD, FF);
    }
}